// Round 19
// baseline (40.165 us; speedup 1.0000x reference)
//
#include <hip/hip_runtime.h>
#include <hip/hip_bf16.h>

namespace {

constexpr int T = 5, F = 30, H = 20;
constexpr int BATCH = 131072;
constexpr int BPB = 64;    // batch rows per block (16 per wave)
constexpr int HRS = 120;   // drain-buffer row stride in halfwords (240 B)

typedef __attribute__((ext_vector_type(8))) short bf16x8;
typedef __attribute__((ext_vector_type(4))) float f32x4;

union Frag16 { unsigned u32[4]; bf16x8 v; };
union Pack2 { __hip_bfloat162 h2; unsigned u; };

__device__ __forceinline__ float sig(float v) {
  return __builtin_amdgcn_rcpf(1.0f + __builtin_amdgcn_exp2f(v * -1.44269504f));
}
// tanh(v) = 2*sigmoid(2v) - 1; saturates correctly at +-inf, no NaN paths.
__device__ __forceinline__ float tanh_s(float v) {
  return fmaf(2.0f,
              __builtin_amdgcn_rcpf(1.0f + __builtin_amdgcn_exp2f(v * -2.88539008f)),
              -1.0f);
}

// ---- single kernel, single launch. Fragments are built inline per-wave
// from global memory (~65 scalar loads/lane, L2/L3-hot: weights are 16 KB
// shared by all 2048 blocks; loads grouped per-m to bound live registers).
// W rows hidx=4*jj+gate, bias folded at k==30 (x virtual col 30 == 1.0);
// U k-axis PERMUTED: slot s=8q+i holds U row 4i+q for i<5, zero otherwise
// -> h-recurrence stays register-local. t-loop touches NO memory at all.
__global__ __launch_bounds__(256, 4) void lstm_main(
    const float* __restrict__ x,
    const float* __restrict__ wf, const float* __restrict__ wi,
    const float* __restrict__ wo, const float* __restrict__ wc,
    const float* __restrict__ uf, const float* __restrict__ ui,
    const float* __restrict__ uo, const float* __restrict__ uc,
    const float* __restrict__ bf, const float* __restrict__ bi,
    const float* __restrict__ bo, const float* __restrict__ bc,
    float* __restrict__ out)
{
  const int tid  = threadIdx.x;
  const int lane = tid & 63;
  const int wv   = tid >> 6;
  const int r15  = lane & 15;
  const int q    = lane >> 4;
  const int b0   = blockIdx.x * BPB;
  const int w0   = 16 * wv;

  const float* xrow = x + (size_t)(b0 + w0 + r15) * (T * F);
  float*       owave = out + (size_t)(b0 + w0) * (T * H); // wave slab, 6.4 KB

  __shared__ __align__(16) unsigned short hist[BPB * HRS]; // 15,360 B drain buf

  // prologue A: burst-load the lane's ENTIRE x panel first (HBM latency is
  // the longest pole; issue these before the L2-hot weight loads).
  // Offsets: k = 8q + {0,2,4}; 4th pair shifted for q==3 (re-reads k28,29)
  // so k=30,31 are never touched; slot {30,31} gets {1.0,0} = bias column.
  const int xo0 = 8 * q, xo1 = 8 * q + 2, xo2 = 8 * q + 4;
  const int xo3 = (q == 3) ? (8 * q + 4) : (8 * q + 6);

  float2 xf[T][4];
#pragma unroll
  for (int t = 0; t < T; ++t) {
    const float* xp = xrow + t * F;
    xf[t][0] = *(const float2*)(xp + xo0);
    xf[t][1] = *(const float2*)(xp + xo1);
    xf[t][2] = *(const float2*)(xp + xo2);
    xf[t][3] = *(const float2*)(xp + xo3);
  }

  // prologue B: inline fragment build from global (no pack kernel).
  const int gA = r15 & 3, jA = r15 >> 2;
  const float* Wg = (gA == 0) ? wf : (gA == 1) ? wi : (gA == 2) ? wo : wc;
  const float* Ug = (gA == 0) ? uf : (gA == 1) ? ui : (gA == 2) ? uo : uc;
  const float* Bg = (gA == 0) ? bf : (gA == 1) ? bi : (gA == 2) ? bo : bc;

  bf16x8 wfrag[5], ufrag[5];
#pragma unroll
  for (int m = 0; m < 5; ++m) {
    const int jj = 4 * m + jA;
    Frag16 fw, fu;
#pragma unroll
    for (int e = 0; e < 4; ++e) {
      const int k0 = 8 * q + 2 * e, k1 = k0 + 1;
      float w0v = (k0 < F) ? Wg[k0 * H + jj] : (k0 == F ? Bg[jj] : 0.f);
      float w1v = (k1 < F) ? Wg[k1 * H + jj] : 0.f;
      Pack2 pw; pw.h2 = __float22bfloat162_rn(float2{w0v, w1v});
      fw.u32[e] = pw.u;
      const int i0 = 2 * e, i1 = 2 * e + 1;          // U slot indices
      float u0 = (i0 < 5) ? Ug[(4 * i0 + q) * H + jj] : 0.f;  // kappa = 4i+q
      float u1 = (i1 < 5) ? Ug[(4 * i1 + q) * H + jj] : 0.f;
      Pack2 pu; pu.h2 = __float22bfloat162_rn(float2{u0, u1});
      fu.u32[e] = pu.u;
    }
    wfrag[m] = fw.v;
    ufrag[m] = fu.v;
  }

  // pack x to bf16 fragments (bias patch baked in)
  unsigned xpk[T][4];
#pragma unroll
  for (int t = 0; t < T; ++t) {
    Pack2 p0, p1, p2, p3;
    p0.h2 = __float22bfloat162_rn(xf[t][0]);
    p1.h2 = __float22bfloat162_rn(xf[t][1]);
    p2.h2 = __float22bfloat162_rn(xf[t][2]);
    p3.h2 = __float22bfloat162_rn(xf[t][3]);
    xpk[t][0] = p0.u;
    xpk[t][1] = p1.u;
    xpk[t][2] = (q == 3) ? p3.u : p2.u;
    xpk[t][3] = (q == 3) ? 0x00003F80u : p3.u;
  }

  float cst[5];
#pragma unroll
  for (int m = 0; m < 5; ++m) cst[m] = 0.f;

  unsigned pd[T][3];                    // packed bf16 h history (static idx)
  unsigned ph0 = 0, ph1 = 0, ph2 = 0;   // previous-t packed h

  // ---- t-loop: NO memory ops (pure MFMA + VALU on registers) ----
#pragma unroll
  for (int t = 0; t < T; ++t) {
    Frag16 fx;
    fx.u32[0] = xpk[t][0];
    fx.u32[1] = xpk[t][1];
    fx.u32[2] = xpk[t][2];
    fx.u32[3] = xpk[t][3];

    f32x4 acc[5];
#pragma unroll
    for (int m = 0; m < 5; ++m)
      acc[m] = __builtin_amdgcn_mfma_f32_16x16x32_bf16(
          wfrag[m], fx.v, f32x4{0.f, 0.f, 0.f, 0.f}, 0, 0, 0);

    if (t > 0) {   // recurrent term: fh = lane's OWN packed h (U k-permuted)
      Frag16 fh;
      fh.u32[0] = ph0;   // {h[m0], h[m1]}
      fh.u32[1] = ph1;   // {h[m2], h[m3]}
      fh.u32[2] = ph2;   // {h[m4], 0}
      fh.u32[3] = 0u;    // zero slots (U rows zero there)
#pragma unroll
      for (int m = 0; m < 5; ++m)
        acc[m] = __builtin_amdgcn_mfma_f32_16x16x32_bf16(
            ufrag[m], fh.v, acc[m], 0, 0, 0);
    }

    // gate math: lane-local (acc[m] = f,i,o,c of hidden jj=4m+q, own row)
    float hn[5];
#pragma unroll
    for (int m = 0; m < 5; ++m) {
      float fg = sig(acc[m][0]);
      float ig = sig(acc[m][1]);
      float og = sig(acc[m][2]);
      float ch = tanh_s(acc[m][3]);
      float cn = fmaf(fg, cst[m], ig * ch);
      cst[m] = cn;
      hn[m] = og * tanh_s(cn);
    }
    {
      Pack2 a, b, c;
      a.h2 = __float22bfloat162_rn(float2{hn[0], hn[1]});
      b.h2 = __float22bfloat162_rn(float2{hn[2], hn[3]});
      c.h2 = __float22bfloat162_rn(float2{hn[4], 0.f});
      ph0 = a.u; ph1 = b.u; ph2 = c.u;
      pd[t][0] = a.u; pd[t][1] = b.u; pd[t][2] = c.u;
    }
  }

  // ---- drain: registers -> LDS (transpose) -> coalesced float4 stores ----
  {
    unsigned short* hrow = hist + (w0 + r15) * HRS;
#pragma unroll
    for (int t = 0; t < T; ++t) {
      hrow[24 * t +  0 + q] = (unsigned short)(pd[t][0]);
      hrow[24 * t +  4 + q] = (unsigned short)(pd[t][0] >> 16);
      hrow[24 * t +  8 + q] = (unsigned short)(pd[t][1]);
      hrow[24 * t + 12 + q] = (unsigned short)(pd[t][1] >> 16);
      hrow[24 * t + 16 + q] = (unsigned short)(pd[t][2]);
    }
  }
  // wave-private rows; within-wave DS ordering is program order -> no barrier.
  // g in [0,400): out dwords 4g..4g+3 = row r=g/25, c4=4*(g%25);
  // src hw = 24*(c4/20) + c4%20 (20%4==0 -> never crosses a t-block).
#pragma unroll
  for (int k = 0; k < 7; ++k) {
    unsigned g = lane + 64 * k;
    if (g < 400) {
      unsigned r = g / 25u, c4 = 4 * (g % 25u);
      unsigned tb = c4 / 20u, j0 = c4 % 20u;
      uint2 pv = *(const uint2*)&hist[(w0 + r) * HRS + 24 * tb + j0];
      float4 v;
      v.x = __uint_as_float(pv.x << 16);
      v.y = __uint_as_float(pv.x & 0xFFFF0000u);
      v.z = __uint_as_float(pv.y << 16);
      v.w = __uint_as_float(pv.y & 0xFFFF0000u);
      *(float4*)(owave + 4 * g) = v;
    }
  }
}

} // namespace

extern "C" void kernel_launch(void* const* d_in, const int* in_sizes, int n_in,
                              void* d_out, int out_size, void* d_ws, size_t ws_size,
                              hipStream_t stream) {
  const float* x  = (const float*)d_in[0];
  const float* wf = (const float*)d_in[1];
  const float* wi = (const float*)d_in[2];
  const float* wo = (const float*)d_in[3];
  const float* wc = (const float*)d_in[4];
  const float* uf = (const float*)d_in[5];
  const float* ui = (const float*)d_in[6];
  const float* uo = (const float*)d_in[7];
  const float* uc = (const float*)d_in[8];
  const float* bf = (const float*)d_in[9];
  const float* bi = (const float*)d_in[10];
  const float* bo = (const float*)d_in[11];
  const float* bc = (const float*)d_in[12];
  float* out = (float*)d_out;

  hipLaunchKernelGGL(lstm_main, dim3(BATCH / BPB), dim3(256), 0, stream,
                     x, wf, wi, wo, wc, uf, ui, uo, uc, bf, bi, bo, bc, out);
}

// Round 20
// 38.144 us; speedup vs baseline: 1.0530x; 1.0530x over previous
//
#include <hip/hip_runtime.h>
#include <hip/hip_bf16.h>

namespace {

constexpr int T = 5, F = 30, H = 20;
constexpr int BATCH = 131072;
constexpr int BPB = 256;   // batch rows per block: 4 waves x 4 groups x 16 rows
constexpr int NG  = 4;     // groups per wave
constexpr int HRS = 120;   // drain-buffer row stride in halfwords (240 B)

typedef __attribute__((ext_vector_type(8))) short bf16x8;
typedef __attribute__((ext_vector_type(4))) float f32x4;

union Frag16 { unsigned u32[4]; bf16x8 v; };
union Pack2 { __hip_bfloat162 h2; unsigned u; };

__device__ __forceinline__ float sig(float v) {
  return __builtin_amdgcn_rcpf(1.0f + __builtin_amdgcn_exp2f(v * -1.44269504f));
}
// tanh(v) = 2*sigmoid(2v) - 1; saturates correctly at +-inf, no NaN paths.
__device__ __forceinline__ float tanh_s(float v) {
  return fmaf(2.0f,
              __builtin_amdgcn_rcpf(1.0f + __builtin_amdgcn_exp2f(v * -2.88539008f)),
              -1.0f);
}

// ---- setup: pre-pack 640 MFMA A-fragments into d_ws (identical to R16) ----
// W (sel=0): identity k; row hidx = 4*jj + gate; bias at k==30; k==31 zero.
// U (sel=1): PERMUTED k-axis: slot s = 8q+i holds U row kappa(s) = 4i+q for
// i<5, ZERO for i>=5 -> the main kernel's h-fragment is register-local.
__global__ void lstm_pack(
    const float* __restrict__ wf, const float* __restrict__ wi,
    const float* __restrict__ wo, const float* __restrict__ wc,
    const float* __restrict__ uf, const float* __restrict__ ui,
    const float* __restrict__ uo, const float* __restrict__ uc,
    const float* __restrict__ bf, const float* __restrict__ bi,
    const float* __restrict__ bo, const float* __restrict__ bc,
    bf16x8* __restrict__ ws)
{
  const int i = blockIdx.x * 256 + threadIdx.x;
  if (i >= 640) return;
  const int lane = i & 63, sel = (i >> 6) & 1, m = i >> 7;
  const int r15 = lane & 15, q = lane >> 4;
  const int gA = r15 & 3, jA = r15 >> 2;
  const int jj = 4 * m + jA;

  const float* Wg = (gA == 0) ? wf : (gA == 1) ? wi : (gA == 2) ? wo : wc;
  const float* Ug = (gA == 0) ? uf : (gA == 1) ? ui : (gA == 2) ? uo : uc;
  const float* Bg = (gA == 0) ? bf : (gA == 1) ? bi : (gA == 2) ? bo : bc;

  Frag16 fr;
#pragma unroll
  for (int e = 0; e < 4; ++e) {
    float v0, v1;
    if (sel == 0) {
      const int k0 = 8 * q + 2 * e, k1 = k0 + 1;
      v0 = (k0 < F) ? Wg[k0 * H + jj] : (k0 == F ? Bg[jj] : 0.f);
      v1 = (k1 < F) ? Wg[k1 * H + jj] : 0.f;
    } else {
      const int i0 = 2 * e, i1 = 2 * e + 1;
      v0 = (i0 < 5) ? Ug[(4 * i0 + q) * H + jj] : 0.f;   // kappa = 4*i + q
      v1 = (i1 < 5) ? Ug[(4 * i1 + q) * H + jj] : 0.f;
    }
    Pack2 p; p.h2 = __float22bfloat162_rn(float2{v0, v1});
    fr.u32[e] = p.u;
  }
  ws[(m * 2 + sel) * 64 + lane] = fr.v;   // [m][sel][lane] -> coalesced reads
}

// ---- main: per-GROUP code identical to R16's memory-free t-loop. Each
// wave sequentially runs NG=4 independent 16-row groups (grid 512, 2048
// waves -> 4x fewer waves, 4x work each). Group g+1's x panel is loaded
// BEFORE group g's compute (independent -> HBM latency hides under MFMA
// + gate math). Fragments loaded once per wave. LDS drain region reused
// across groups (program order).
__global__ __launch_bounds__(256, 2) void lstm_main(
    const float* __restrict__ x,
    const bf16x8* __restrict__ wsfrag,
    float* __restrict__ out)
{
  const int tid  = threadIdx.x;
  const int lane = tid & 63;
  const int wv   = tid >> 6;
  const int r15  = lane & 15;
  const int q    = lane >> 4;
  const int b0   = blockIdx.x * BPB;
  const int wbase = b0 + wv * (NG * 16);   // wave's 64 contiguous rows
  const int w0   = 16 * wv;                // block-local LDS row base

  __shared__ __align__(16) unsigned short hist[64 * HRS]; // 15,360 B drain buf

  // prologue A: 10 coalesced dwordx4 fragment loads (once per wave)
  bf16x8 wfrag[5], ufrag[5];
#pragma unroll
  for (int m = 0; m < 5; ++m) {
    wfrag[m] = wsfrag[(m * 2 + 0) * 64 + lane];
    ufrag[m] = wsfrag[(m * 2 + 1) * 64 + lane];
  }

  // x offsets: k = 8q + {0,2,4}; 4th pair shifted for q==3 (re-reads k28,29)
  // so k=30,31 never touched; slot {30,31} gets {1.0,0} = bias column.
  const int xo0 = 8 * q, xo1 = 8 * q + 2, xo2 = 8 * q + 4;
  const int xo3 = (q == 3) ? (8 * q + 4) : (8 * q + 6);

  // load group 0's x panel
  float2 xf[T][4];
  {
    const float* xrow = x + (size_t)(wbase + r15) * (T * F);
#pragma unroll
    for (int t = 0; t < T; ++t) {
      const float* xp = xrow + t * F;
      xf[t][0] = *(const float2*)(xp + xo0);
      xf[t][1] = *(const float2*)(xp + xo1);
      xf[t][2] = *(const float2*)(xp + xo2);
      xf[t][3] = *(const float2*)(xp + xo3);
    }
  }

#pragma unroll
  for (int grp = 0; grp < NG; ++grp) {
    // pack current group's x to bf16 fragments (bias patch baked in)
    unsigned xpk[T][4];
#pragma unroll
    for (int t = 0; t < T; ++t) {
      Pack2 p0, p1, p2, p3;
      p0.h2 = __float22bfloat162_rn(xf[t][0]);
      p1.h2 = __float22bfloat162_rn(xf[t][1]);
      p2.h2 = __float22bfloat162_rn(xf[t][2]);
      p3.h2 = __float22bfloat162_rn(xf[t][3]);
      xpk[t][0] = p0.u;
      xpk[t][1] = p1.u;
      xpk[t][2] = (q == 3) ? p3.u : p2.u;
      xpk[t][3] = (q == 3) ? 0x00003F80u : p3.u;
    }

    // T14: issue NEXT group's x loads now; latency hides under this group's
    // compute (groups are fully independent).
    if (grp + 1 < NG) {
      const float* xrow = x + (size_t)(wbase + (grp + 1) * 16 + r15) * (T * F);
#pragma unroll
      for (int t = 0; t < T; ++t) {
        const float* xp = xrow + t * F;
        xf[t][0] = *(const float2*)(xp + xo0);
        xf[t][1] = *(const float2*)(xp + xo1);
        xf[t][2] = *(const float2*)(xp + xo2);
        xf[t][3] = *(const float2*)(xp + xo3);
      }
    }

    float cst[5];
#pragma unroll
    for (int m = 0; m < 5; ++m) cst[m] = 0.f;

    unsigned pd[T][3];                    // packed bf16 h history (static idx)
    unsigned ph0 = 0, ph1 = 0, ph2 = 0;   // previous-t packed h

    // t-loop: NO memory ops (pure MFMA + VALU on registers)
#pragma unroll
    for (int t = 0; t < T; ++t) {
      Frag16 fx;
      fx.u32[0] = xpk[t][0];
      fx.u32[1] = xpk[t][1];
      fx.u32[2] = xpk[t][2];
      fx.u32[3] = xpk[t][3];

      f32x4 acc[5];
#pragma unroll
      for (int m = 0; m < 5; ++m)
        acc[m] = __builtin_amdgcn_mfma_f32_16x16x32_bf16(
            wfrag[m], fx.v, f32x4{0.f, 0.f, 0.f, 0.f}, 0, 0, 0);

      if (t > 0) {   // recurrent: fh = lane's OWN packed h (U k-permuted)
        Frag16 fh;
        fh.u32[0] = ph0;   // {h[m0], h[m1]}
        fh.u32[1] = ph1;   // {h[m2], h[m3]}
        fh.u32[2] = ph2;   // {h[m4], 0}
        fh.u32[3] = 0u;    // zero slots (U rows zero there)
#pragma unroll
        for (int m = 0; m < 5; ++m)
          acc[m] = __builtin_amdgcn_mfma_f32_16x16x32_bf16(
              ufrag[m], fh.v, acc[m], 0, 0, 0);
      }

      // gate math: lane-local (acc[m] = f,i,o,c of hidden jj=4m+q, own row)
      float hn[5];
#pragma unroll
      for (int m = 0; m < 5; ++m) {
        float fg = sig(acc[m][0]);
        float ig = sig(acc[m][1]);
        float og = sig(acc[m][2]);
        float ch = tanh_s(acc[m][3]);
        float cn = fmaf(fg, cst[m], ig * ch);
        cst[m] = cn;
        hn[m] = og * tanh_s(cn);
      }
      {
        Pack2 a, b, c;
        a.h2 = __float22bfloat162_rn(float2{hn[0], hn[1]});
        b.h2 = __float22bfloat162_rn(float2{hn[2], hn[3]});
        c.h2 = __float22bfloat162_rn(float2{hn[4], 0.f});
        ph0 = a.u; ph1 = b.u; ph2 = c.u;
        pd[t][0] = a.u; pd[t][1] = b.u; pd[t][2] = c.u;
      }
    }

    // drain this group: registers -> LDS transpose -> coalesced float4.
    // Wave-private LDS region reused across groups (program order).
    {
      unsigned short* hrow = hist + (w0 + r15) * HRS;
#pragma unroll
      for (int t = 0; t < T; ++t) {
        hrow[24 * t +  0 + q] = (unsigned short)(pd[t][0]);
        hrow[24 * t +  4 + q] = (unsigned short)(pd[t][0] >> 16);
        hrow[24 * t +  8 + q] = (unsigned short)(pd[t][1]);
        hrow[24 * t + 12 + q] = (unsigned short)(pd[t][1] >> 16);
        hrow[24 * t + 16 + q] = (unsigned short)(pd[t][2]);
      }
    }
    float* ogrp = out + (size_t)(wbase + grp * 16) * (T * H);
#pragma unroll
    for (int k = 0; k < 7; ++k) {
      unsigned g = lane + 64 * k;
      if (g < 400) {
        unsigned r = g / 25u, c4 = 4 * (g % 25u);
        unsigned tb = c4 / 20u, j0 = c4 % 20u;
        uint2 pv = *(const uint2*)&hist[(w0 + r) * HRS + 24 * tb + j0];
        float4 v;
        v.x = __uint_as_float(pv.x << 16);
        v.y = __uint_as_float(pv.x & 0xFFFF0000u);
        v.z = __uint_as_float(pv.y << 16);
        v.w = __uint_as_float(pv.y & 0xFFFF0000u);
        *(float4*)(ogrp + 4 * g) = v;
      }
    }
  }
}

} // namespace

extern "C" void kernel_launch(void* const* d_in, const int* in_sizes, int n_in,
                              void* d_out, int out_size, void* d_ws, size_t ws_size,
                              hipStream_t stream) {
  const float* x  = (const float*)d_in[0];
  const float* wf = (const float*)d_in[1];
  const float* wi = (const float*)d_in[2];
  const float* wo = (const float*)d_in[3];
  const float* wc = (const float*)d_in[4];
  const float* uf = (const float*)d_in[5];
  const float* ui = (const float*)d_in[6];
  const float* uo = (const float*)d_in[7];
  const float* uc = (const float*)d_in[8];
  const float* bf = (const float*)d_in[9];
  const float* bi = (const float*)d_in[10];
  const float* bo = (const float*)d_in[11];
  const float* bc = (const float*)d_in[12];
  float* out = (float*)d_out;
  bf16x8* ws = (bf16x8*)d_ws;   // needs 10,240 B

  hipLaunchKernelGGL(lstm_pack, dim3(3), dim3(256), 0, stream,
                     wf, wi, wo, wc, uf, ui, uo, uc, bf, bi, bo, bc, ws);
  hipLaunchKernelGGL(lstm_main, dim3(BATCH / BPB), dim3(256), 0, stream,
                     x, ws, out);
}